// Round 12
// baseline (254.443 us; speedup 1.0000x reference)
//
#include <hip/hip_runtime.h>
#include <cmath>

#define B_ 2
#define S_ 2048
#define D_ 1024
#define H_ 16
#define HD_ 64
#define M_ 4096   // B*S

typedef __attribute__((ext_vector_type(8))) short short8;
typedef __attribute__((ext_vector_type(4))) short short4v;
typedef __attribute__((ext_vector_type(4))) float f32x4;

// round-to-nearest-even f32 -> bf16 (values finite here)
__device__ __forceinline__ short f2bf(float x) {
    unsigned u = __builtin_bit_cast(unsigned, x);
    u += 0x7fffu + ((u >> 16) & 1u);
    return (short)(u >> 16);
}

__device__ __forceinline__ void gload_lds16(const short* g, short* l) {
    __builtin_amdgcn_global_load_lds(
        (const __attribute__((address_space(1))) unsigned int*)g,
        (__attribute__((address_space(3))) unsigned int*)l, 16, 0, 0);
}

// counted vmcnt wait — prefetches stay in flight across barriers
template<int N> __device__ __forceinline__ void vwait() {
    if constexpr (N == 0) asm volatile("s_waitcnt vmcnt(0)" ::: "memory");
    else if constexpr (N == 2) asm volatile("s_waitcnt vmcnt(2)" ::: "memory");
    else if constexpr (N == 3) asm volatile("s_waitcnt vmcnt(3)" ::: "memory");
    else if constexpr (N == 4) asm volatile("s_waitcnt vmcnt(4)" ::: "memory");
}
__device__ __forceinline__ void bar() { __builtin_amdgcn_s_barrier(); }

// ---------------------------------------------------------------------------
// cast fp32 inputs to bf16
__global__ __launch_bounds__(256) void cast_all_kernel(
    const float* __restrict__ x,  const float* __restrict__ Wq,
    const float* __restrict__ Wk, const float* __restrict__ Wv,
    const float* __restrict__ Wo,
    short* __restrict__ xb, short* __restrict__ Wqkvb, short* __restrict__ Wob)
{
    const size_t i = (size_t)blockIdx.x * 256 + threadIdx.x;  // float4 index
    const float* src; short* dst; size_t off;
    if (i < 1048576)      { src = x;  dst = xb;              off = i; }
    else if (i < 1310720) { src = Wq; dst = Wqkvb;           off = i - 1048576; }
    else if (i < 1572864) { src = Wk; dst = Wqkvb + 1048576; off = i - 1310720; }
    else if (i < 1835008) { src = Wv; dst = Wqkvb + 2097152; off = i - 1572864; }
    else                  { src = Wo; dst = Wob;             off = i - 1835008; }
    float4 v = ((const float4*)src)[off];
    short4v o = { f2bf(v.x), f2bf(v.y), f2bf(v.z), f2bf(v.w) };
    ((short4v*)dst)[off] = o;
}

// ---------------------------------------------------------------------------
// QKV GEMM — sa2 stage-ahead-2, BK=32, 128x128, R9 verbatim (best measured).
// 3 static buffers; per chunk: vwait<4> -> s_barrier -> STAGE(c+2) -> COMP(c).
// LDS rows 32 shorts (64B); data slot s of row r at LDS slot s^((r>>1)&3).
// 48 KB LDS -> 3 blocks/CU, grid (24,32) all-resident.
// Fused epilogue: q,k bias+RoPE -> [BH,S,HD]; v bias -> [BH,HD,S].
__global__ __launch_bounds__(256) void gemm_qkv(
    const short* __restrict__ A, const short* __restrict__ Bw,
    const float* __restrict__ b0p, const float* __restrict__ b1p, const float* __restrict__ b2p,
    const float* __restrict__ freqs,
    short* __restrict__ out0, short* __restrict__ out1, short* __restrict__ out2)
{
    constexpr int TM = 128, TN = 128, RT = 4, CT = 4, LPC = 4;
    __shared__ __align__(16) short A0[TM*32];
    __shared__ __align__(16) short A1[TM*32];
    __shared__ __align__(16) short A2[TM*32];
    __shared__ __align__(16) short B0[TN*32];
    __shared__ __align__(16) short B1[TN*32];
    __shared__ __align__(16) short B2[TN*32];
    const int t = threadIdx.x;
    const int w = t >> 6;
    const int lane = t & 63;
    const int qd = lane >> 4, l = lane & 15;
    const int n0 = blockIdx.x * TN, m0 = blockIdx.y * TM;
    const int wr = (w >> 1) * (TM/2), wc = (w & 1) * (TN/2);
    const int srow  = lane >> 2;
    const int sslot = ((lane & 3) ^ ((lane >> 3) & 3)) * 8;
    const int rsw = (l >> 1) & 3;

    f32x4 acc[RT][CT] = {};

    auto STAGE = [&](int c, short* As, short* Bss) {
        const int k0 = c * 32;
        #pragma unroll
        for (int j = 0; j < TM/64; ++j) {
            const int r0 = (j*4 + w) * 16;
            gload_lds16(A + (size_t)(m0 + r0 + srow)*1024 + k0 + sslot, &As[r0*32]);
        }
        #pragma unroll
        for (int j = 0; j < TN/64; ++j) {
            const int r0 = (j*4 + w) * 16;
            gload_lds16(Bw + (size_t)(n0 + r0 + srow)*1024 + k0 + sslot, &Bss[r0*32]);
        }
    };

    auto COMP = [&](const short* As, const short* Bss) {
        short8 af[RT], bfr[CT];
        #pragma unroll
        for (int rt = 0; rt < RT; ++rt)
            af[rt] = *(const short8*)&As[(wr + rt*16 + l)*32 + ((qd ^ rsw) << 3)];
        #pragma unroll
        for (int ct = 0; ct < CT; ++ct)
            bfr[ct] = *(const short8*)&Bss[(wc + ct*16 + l)*32 + ((qd ^ rsw) << 3)];
        #pragma unroll
        for (int rt = 0; rt < RT; ++rt)
            #pragma unroll
            for (int ct = 0; ct < CT; ++ct)
                acc[rt][ct] = __builtin_amdgcn_mfma_f32_16x16x32_bf16(af[rt], bfr[ct], acc[rt][ct], 0, 0, 0);
    };

    STAGE(0, A0, B0);
    STAGE(1, A1, B1);
    for (int p = 0; p <= 27; p += 3) {
        vwait<LPC>(); bar();
        STAGE(p + 2, A2, B2);
        COMP(A0, B0);
        vwait<LPC>(); bar();
        STAGE(p + 3, A0, B0);
        COMP(A1, B1);
        vwait<LPC>(); bar();
        STAGE(p + 4, A1, B1);
        COMP(A2, B2);
    }
    vwait<LPC>(); bar();
    COMP(A0, B0);
    vwait<0>(); bar();
    COMP(A1, B1);

    const int sel = n0 >> 10;          // 0=q 1=k 2=v (uniform per block)
    const int nb = n0 & 1023;
    const float* bias = (sel == 0) ? b0p : (sel == 1) ? b1p : b2p;
    if (sel < 2) {
        short* outg = (sel == 0) ? out0 : out1;
        #pragma unroll
        for (int rt = 0; rt < RT; ++rt)
            #pragma unroll
            for (int ct = 0; ct < CT; ++ct) {
                const int d = nb + wc + ct*16 + l;
                const float bsv = bias[d];
                const int h = d >> 6, hd = d & 63;
                #pragma unroll
                for (int r = 0; r < 4; ++r) {
                    const int m = m0 + wr + rt*16 + qd*4 + r;
                    const int bb = m >> 11, s = m & 2047;
                    float val = acc[rt][ct][r] + bsv;
                    float pv = __shfl_xor(val, 1);
                    const float* f = freqs + (size_t)s*128 + (size_t)(hd >> 1)*4;
                    float o = (d & 1) ? (f[2]*pv + f[3]*val) : (f[0]*val + f[1]*pv);
                    outg[((size_t)(bb*16 + h)*2048 + s)*64 + hd] = f2bf(o);
                }
            }
    } else {
        #pragma unroll
        for (int rt = 0; rt < RT; ++rt)
            #pragma unroll
            for (int ct = 0; ct < CT; ++ct) {
                const int d = nb + wc + ct*16 + l;
                const float bsv = bias[d];
                const int h = d >> 6, hd = d & 63;
                const int m0r = m0 + wr + rt*16 + qd*4;
                const int bb = m0r >> 11, s0 = m0r & 2047;
                short4v pk;
                #pragma unroll
                for (int r = 0; r < 4; ++r) pk[r] = f2bf(acc[rt][ct][r] + bsv);
                *(short4v*)&out2[((size_t)(bb*16 + h)*64 + hd)*2048 + s0] = pk;  // v^T
            }
    }
}

// ---------------------------------------------------------------------------
// proj GEMM — BK=64, 64x64 tile, sa2 counted stage-ahead-2. 16 chunks
// (half the periods of the BK=32 version: attn/proj are period-bound, not
// interleave-bound — R11's grid-doubling was null). 3 static buffers,
// 48 KB LDS -> 3 blocks/CU, grid (16,64)=1024.
// LDS rows 64 shorts (128B); data slot s of row r at LDS slot s^(r&7)
// (gemm_2ph/attn swizzle, correctness-verified R6+). Per chunk: 4 gloads,
// 8 MFMA/wave; vwait<4> -> bar -> STAGE(c+2) -> COMP(c).
__global__ __launch_bounds__(256) void gemm_proj64(
    const short* __restrict__ A, const short* __restrict__ Bw,
    const float* __restrict__ b0p, float* __restrict__ out)
{
    __shared__ __align__(16) short A0[64*64];
    __shared__ __align__(16) short A1[64*64];
    __shared__ __align__(16) short A2[64*64];
    __shared__ __align__(16) short B0[64*64];
    __shared__ __align__(16) short B1[64*64];
    __shared__ __align__(16) short B2[64*64];
    const int t = threadIdx.x;
    const int w = t >> 6;
    const int lane = t & 63;
    const int qd = lane >> 4, l = lane & 15;
    const int l7 = lane & 7;
    const int n0 = blockIdx.x * 64, m0 = blockIdx.y * 64;
    const int wr = (w >> 1) * 32, wc = (w & 1) * 32;
    // staging: one gload = 8 rows x 128B; lane -> (row lane>>3, slot lane&7)
    const int rl  = lane >> 3;
    const int ss8 = ((lane & 7) ^ rl) << 3;    // pre-swizzled source slot

    f32x4 acc[2][2] = {};

    auto STAGE = [&](int c, short* As, short* Bss) {
        const int k0 = c * 64;
        #pragma unroll
        for (int j = 0; j < 2; ++j) {
            const int r0 = (j*4 + w) * 8;
            gload_lds16(A  + (size_t)(m0 + r0 + rl)*1024 + k0 + ss8, &As[r0*64]);
            gload_lds16(Bw + (size_t)(n0 + r0 + rl)*1024 + k0 + ss8, &Bss[r0*64]);
        }
    };

    auto COMP = [&](const short* As, const short* Bss) {
        #pragma unroll
        for (int kk = 0; kk < 2; ++kk) {
            short8 af[2], bfr[2];
            #pragma unroll
            for (int rt = 0; rt < 2; ++rt)
                af[rt] = *(const short8*)&As[(wr + rt*16 + l)*64 + (((kk*4 + qd) ^ l7) << 3)];
            #pragma unroll
            for (int ct = 0; ct < 2; ++ct)
                bfr[ct] = *(const short8*)&Bss[(wc + ct*16 + l)*64 + (((kk*4 + qd) ^ l7) << 3)];
            #pragma unroll
            for (int rt = 0; rt < 2; ++rt)
                #pragma unroll
                for (int ct = 0; ct < 2; ++ct)
                    acc[rt][ct] = __builtin_amdgcn_mfma_f32_16x16x32_bf16(af[rt], bfr[ct], acc[rt][ct], 0, 0, 0);
        }
    };

    // 16 chunks of K=64; chunk c -> buffer c%3; stage-ahead-2, 1 barrier/chunk.
    STAGE(0, A0, B0);
    STAGE(1, A1, B1);
    for (int p = 0; p <= 9; p += 3) {       // computes 0..11, stages 2..13
        vwait<4>(); bar();
        STAGE(p + 2, A2, B2);
        COMP(A0, B0);
        vwait<4>(); bar();
        STAGE(p + 3, A0, B0);
        COMP(A1, B1);
        vwait<4>(); bar();
        STAGE(p + 4, A1, B1);
        COMP(A2, B2);
    }
    vwait<4>(); bar();
    STAGE(14, A2, B2);
    COMP(A0, B0);                           // chunk 12
    vwait<4>(); bar();
    STAGE(15, A0, B0);
    COMP(A1, B1);                           // chunk 13
    vwait<4>(); bar();
    COMP(A2, B2);                           // chunk 14
    vwait<0>(); bar();
    COMP(A0, B0);                           // chunk 15

    #pragma unroll
    for (int rt = 0; rt < 2; ++rt)
        #pragma unroll
        for (int ct = 0; ct < 2; ++ct) {
            const int n = n0 + wc + ct*16 + l;
            const float bias = b0p[n];
            #pragma unroll
            for (int r = 0; r < 4; ++r) {
                const int m = m0 + wr + rt*16 + qd*4 + r;
                out[(size_t)m*1024 + n] = acc[rt][ct][r] + bias;
            }
        }
}

// ---------------------------------------------------------------------------
// MFMA flash attention — R12: pair-period double-buffer. 8 waves x 16 q.
// TWO K-tiles per barrier period -> 16 barriers instead of 32 (attn is
// period-bound; sa2's barrier halving was this session's one solid win).
// 4 single-tile buffer pairs in 2 sets {Ka,Kb}/{Kc,Kd}; per period:
// vmcnt(0) (drains the pair issued ONE FULL period (~2 TILEs) earlier ->
// near-free, unlike R4's same-period drain) -> bar -> PREF next pair (into
// the set all waves finished reading before this bar) -> TILE x2.
// K/V^T staged via global_load_lds with PRE-SWIZZLED global source (16B
// slot s of row r holds slot s^(r&7), 128B rows); all b128 reads apply the
// same XOR -> conflict-free. P in a separate buffer (wave-local rows).
// LDS 80 KB -> 2 blocks/CU (same as R9), grid (16,32).
__global__ __launch_bounds__(512) void attn_mfma(
    const short* __restrict__ qg, const short* __restrict__ kg,
    const short* __restrict__ vtg, short* __restrict__ og)
{
    __shared__ __align__(16) short Ka[64*64];
    __shared__ __align__(16) short Kb[64*64];
    __shared__ __align__(16) short Kc[64*64];
    __shared__ __align__(16) short Kd[64*64];
    __shared__ __align__(16) short Va[64*64];
    __shared__ __align__(16) short Vb[64*64];
    __shared__ __align__(16) short Vc[64*64];
    __shared__ __align__(16) short Vd[64*64];
    __shared__ __align__(16) short Pb[128*64];

    const int t = threadIdx.x;
    const int w = t >> 6;                  // 0..7
    const int lane = t & 63;
    const int qd = lane >> 4, l = lane & 15;
    const int l7 = lane & 7;
    const int q0 = blockIdx.x * 128;
    const int bh = blockIdx.y;

    const int rl  = lane >> 3;
    const int ss8 = ((lane & 7) ^ rl) << 3;

    short8 qf[2];
    const short* qb = qg + ((size_t)bh*2048 + q0 + w*16)*64;
    #pragma unroll
    for (int kf = 0; kf < 2; ++kf)
        qf[kf] = *(const short8*)&qb[l*64 + kf*32 + qd*8];

    f32x4 oacc[4] = {};
    float lsum = 0.f;

    const short* kbase = kg  + (size_t)bh*2048*64;
    const short* vbase = vtg + (size_t)bh*64*2048;
    const float SC = 0.125f * 1.44269504088896340736f;

    auto PREF = [&](int c, short* Kdst, short* Vdst) {
        gload_lds16(kbase + (size_t)(c*64 + w*8 + rl)*64 + ss8,   &Kdst[(w*8)*64]);
        gload_lds16(vbase + (size_t)(w*8 + rl)*2048 + c*64 + ss8, &Vdst[(w*8)*64]);
    };

    auto TILE = [&](const short* Kc_, const short* Vc_) {
        f32x4 sacc[4] = {};
        #pragma unroll
        for (int ct = 0; ct < 4; ++ct) {
            short8 k0f = *(const short8*)&Kc_[(ct*16 + l)*64 + (((0 + qd) ^ l7) << 3)];
            short8 k1f = *(const short8*)&Kc_[(ct*16 + l)*64 + (((4 + qd) ^ l7) << 3)];
            sacc[ct] = __builtin_amdgcn_mfma_f32_16x16x32_bf16(k0f, qf[0], sacc[ct], 0, 0, 0);
            sacc[ct] = __builtin_amdgcn_mfma_f32_16x16x32_bf16(k1f, qf[1], sacc[ct], 0, 0, 0);
        }
        #pragma unroll
        for (int ct = 0; ct < 4; ++ct) {
            float p0 = exp2f(sacc[ct][0] * SC);
            float p1 = exp2f(sacc[ct][1] * SC);
            float p2 = exp2f(sacc[ct][2] * SC);
            float p3 = exp2f(sacc[ct][3] * SC);
            lsum += (p0 + p1) + (p2 + p3);
            union { unsigned u[2]; short4v s; } cv;
            asm("v_cvt_pk_bf16_f32 %0, %1, %2" : "=v"(cv.u[0]) : "v"(p0), "v"(p1));
            asm("v_cvt_pk_bf16_f32 %0, %1, %2" : "=v"(cv.u[1]) : "v"(p2), "v"(p3));
            *(short4v*)&Pb[(w*16 + l)*64 + (((ct*32 + qd*8) ^ (l7 << 4)) >> 1)] = cv.s;
        }
        #pragma unroll
        for (int kf = 0; kf < 2; ++kf) {
            const int so = ((kf*4 + qd) ^ l7) << 3;
            short8 pa = *(const short8*)&Pb[(w*16 + l)*64 + so];
            #pragma unroll
            for (int ht = 0; ht < 4; ++ht) {
                short8 vb = *(const short8*)&Vc_[(ht*16 + l)*64 + so];
                oacc[ht] = __builtin_amdgcn_mfma_f32_16x16x32_bf16(pa, vb, oacc[ht], 0, 0, 0);
            }
        }
    };

    // 32 tiles = 16 pairs; set0={Ka,Kb}, set1={Kc,Kd}; pair p -> set p%2.
    PREF(0, Ka, Va); PREF(1, Kb, Vb);          // pair 0
    for (int P = 0; P < 16; P += 2) {
        vwait<0>(); bar();                     // pair P landed (issued 1 period ago)
        if (P < 15) { PREF(2*P + 2, Kc, Vc); PREF(2*P + 3, Kd, Vd); }   // pair P+1
        TILE(Ka, Va); TILE(Kb, Vb);            // tiles 2P, 2P+1
        vwait<0>(); bar();                     // pair P+1 landed
        if (P + 2 < 16) { PREF(2*P + 4, Ka, Va); PREF(2*P + 5, Kb, Vb); } // pair P+2
        TILE(Kc, Vc); TILE(Kd, Vd);            // tiles 2P+2, 2P+3
    }

    lsum += __shfl_xor(lsum, 16);
    lsum += __shfl_xor(lsum, 32);
    float inv[4];
    #pragma unroll
    for (int r = 0; r < 4; ++r)
        inv[r] = 1.0f / __shfl(lsum, qd*4 + r);

    const int bb = bh >> 4, h = bh & 15;
    #pragma unroll
    for (int ht = 0; ht < 4; ++ht)
        #pragma unroll
        for (int r = 0; r < 4; ++r) {
            const int s = q0 + w*16 + qd*4 + r;
            og[((size_t)bb*2048 + s)*1024 + h*64 + ht*16 + l] =
                f2bf(oacc[ht][r] * inv[r]);
        }
}

// ---------------------------------------------------------------------------
extern "C" void kernel_launch(void* const* d_in, const int* in_sizes, int n_in,
                              void* d_out, int out_size, void* d_ws, size_t ws_size,
                              hipStream_t stream)
{
    const float* x  = (const float*)d_in[0];
    const float* fr = (const float*)d_in[1];
    const float* Wq = (const float*)d_in[2];
    const float* bq = (const float*)d_in[3];
    const float* Wk = (const float*)d_in[4];
    const float* bk = (const float*)d_in[5];
    const float* Wv = (const float*)d_in[6];
    const float* bv = (const float*)d_in[7];
    const float* Wo = (const float*)d_in[8];
    const float* bo = (const float*)d_in[9];
    float* out = (float*)d_out;

    short* ws    = (short*)d_ws;
    short* xb    = ws;                  // 4,194,304
    short* Wqkvb = xb    + 4194304;     // 3,145,728
    short* Wob   = Wqkvb + 3145728;     // 1,048,576
    short* qg    = Wob   + 1048576;     // [BH,S,HD]
    short* kg    = qg    + 4194304;     // [BH,S,HD]
    short* vtg   = kg    + 4194304;     // [BH,HD,S]
    short* og    = vtg   + 4194304;     // [B,S,H*HD]

    cast_all_kernel<<<8192, 256, 0, stream>>>(x, Wq, Wk, Wv, Wo, xb, Wqkvb, Wob);
    gemm_qkv<<<dim3(24, 32), 256, 0, stream>>>(xb, Wqkvb, bq, bk, bv, fr, qg, kg, vtg);
    attn_mfma<<<dim3(16, 32), 512, 0, stream>>>(qg, kg, vtg, og);
    gemm_proj64<<<dim3(16, 64), 256, 0, stream>>>(og, Wob, bo, out);
}

// Round 13
// 240.525 us; speedup vs baseline: 1.0579x; 1.0579x over previous
//
#include <hip/hip_runtime.h>
#include <cmath>

#define B_ 2
#define S_ 2048
#define D_ 1024
#define H_ 16
#define HD_ 64
#define M_ 4096   // B*S

typedef __attribute__((ext_vector_type(8))) short short8;
typedef __attribute__((ext_vector_type(4))) short short4v;
typedef __attribute__((ext_vector_type(4))) float f32x4;

// round-to-nearest-even f32 -> bf16 (values finite here)
__device__ __forceinline__ short f2bf(float x) {
    unsigned u = __builtin_bit_cast(unsigned, x);
    u += 0x7fffu + ((u >> 16) & 1u);
    return (short)(u >> 16);
}

__device__ __forceinline__ void gload_lds16(const short* g, short* l) {
    __builtin_amdgcn_global_load_lds(
        (const __attribute__((address_space(1))) unsigned int*)g,
        (__attribute__((address_space(3))) unsigned int*)l, 16, 0, 0);
}

// counted vmcnt wait — prefetches stay in flight across barriers
template<int N> __device__ __forceinline__ void vwait() {
    if constexpr (N == 0) asm volatile("s_waitcnt vmcnt(0)" ::: "memory");
    else if constexpr (N == 2) asm volatile("s_waitcnt vmcnt(2)" ::: "memory");
    else if constexpr (N == 3) asm volatile("s_waitcnt vmcnt(3)" ::: "memory");
    else if constexpr (N == 4) asm volatile("s_waitcnt vmcnt(4)" ::: "memory");
}
__device__ __forceinline__ void bar() { __builtin_amdgcn_s_barrier(); }

// ---------------------------------------------------------------------------
// cast fp32 inputs to bf16
__global__ __launch_bounds__(256) void cast_all_kernel(
    const float* __restrict__ x,  const float* __restrict__ Wq,
    const float* __restrict__ Wk, const float* __restrict__ Wv,
    const float* __restrict__ Wo,
    short* __restrict__ xb, short* __restrict__ Wqkvb, short* __restrict__ Wob)
{
    const size_t i = (size_t)blockIdx.x * 256 + threadIdx.x;  // float4 index
    const float* src; short* dst; size_t off;
    if (i < 1048576)      { src = x;  dst = xb;              off = i; }
    else if (i < 1310720) { src = Wq; dst = Wqkvb;           off = i - 1048576; }
    else if (i < 1572864) { src = Wk; dst = Wqkvb + 1048576; off = i - 1310720; }
    else if (i < 1835008) { src = Wv; dst = Wqkvb + 2097152; off = i - 1572864; }
    else                  { src = Wo; dst = Wob;             off = i - 1835008; }
    float4 v = ((const float4*)src)[off];
    short4v o = { f2bf(v.x), f2bf(v.y), f2bf(v.z), f2bf(v.w) };
    ((short4v*)dst)[off] = o;
}

// ---------------------------------------------------------------------------
// QKV GEMM — sa2 stage-ahead-2, BK=32, 128x128 (R9 verbatim, best measured).
// 3 static buffers; per chunk: vwait<4> -> s_barrier -> STAGE(c+2) -> COMP(c).
// LDS rows 32 shorts (64B); data slot s of row r at LDS slot s^((r>>1)&3).
// 48 KB LDS -> 3 blocks/CU, grid (24,32) all-resident.
// Fused epilogue: q,k bias+RoPE -> [BH,S,HD]; v bias -> [BH,HD,S].
__global__ __launch_bounds__(256) void gemm_qkv(
    const short* __restrict__ A, const short* __restrict__ Bw,
    const float* __restrict__ b0p, const float* __restrict__ b1p, const float* __restrict__ b2p,
    const float* __restrict__ freqs,
    short* __restrict__ out0, short* __restrict__ out1, short* __restrict__ out2)
{
    constexpr int TM = 128, TN = 128, RT = 4, CT = 4, LPC = 4;
    __shared__ __align__(16) short A0[TM*32];
    __shared__ __align__(16) short A1[TM*32];
    __shared__ __align__(16) short A2[TM*32];
    __shared__ __align__(16) short B0[TN*32];
    __shared__ __align__(16) short B1[TN*32];
    __shared__ __align__(16) short B2[TN*32];
    const int t = threadIdx.x;
    const int w = t >> 6;
    const int lane = t & 63;
    const int qd = lane >> 4, l = lane & 15;
    const int n0 = blockIdx.x * TN, m0 = blockIdx.y * TM;
    const int wr = (w >> 1) * (TM/2), wc = (w & 1) * (TN/2);
    const int srow  = lane >> 2;
    const int sslot = ((lane & 3) ^ ((lane >> 3) & 3)) * 8;
    const int rsw = (l >> 1) & 3;

    f32x4 acc[RT][CT] = {};

    auto STAGE = [&](int c, short* As, short* Bss) {
        const int k0 = c * 32;
        #pragma unroll
        for (int j = 0; j < TM/64; ++j) {
            const int r0 = (j*4 + w) * 16;
            gload_lds16(A + (size_t)(m0 + r0 + srow)*1024 + k0 + sslot, &As[r0*32]);
        }
        #pragma unroll
        for (int j = 0; j < TN/64; ++j) {
            const int r0 = (j*4 + w) * 16;
            gload_lds16(Bw + (size_t)(n0 + r0 + srow)*1024 + k0 + sslot, &Bss[r0*32]);
        }
    };

    auto COMP = [&](const short* As, const short* Bss) {
        short8 af[RT], bfr[CT];
        #pragma unroll
        for (int rt = 0; rt < RT; ++rt)
            af[rt] = *(const short8*)&As[(wr + rt*16 + l)*32 + ((qd ^ rsw) << 3)];
        #pragma unroll
        for (int ct = 0; ct < CT; ++ct)
            bfr[ct] = *(const short8*)&Bss[(wc + ct*16 + l)*32 + ((qd ^ rsw) << 3)];
        #pragma unroll
        for (int rt = 0; rt < RT; ++rt)
            #pragma unroll
            for (int ct = 0; ct < CT; ++ct)
                acc[rt][ct] = __builtin_amdgcn_mfma_f32_16x16x32_bf16(af[rt], bfr[ct], acc[rt][ct], 0, 0, 0);
    };

    STAGE(0, A0, B0);
    STAGE(1, A1, B1);
    for (int p = 0; p <= 27; p += 3) {
        vwait<LPC>(); bar();
        STAGE(p + 2, A2, B2);
        COMP(A0, B0);
        vwait<LPC>(); bar();
        STAGE(p + 3, A0, B0);
        COMP(A1, B1);
        vwait<LPC>(); bar();
        STAGE(p + 4, A1, B1);
        COMP(A2, B2);
    }
    vwait<LPC>(); bar();
    COMP(A0, B0);
    vwait<0>(); bar();
    COMP(A1, B1);

    const int sel = n0 >> 10;          // 0=q 1=k 2=v (uniform per block)
    const int nb = n0 & 1023;
    const float* bias = (sel == 0) ? b0p : (sel == 1) ? b1p : b2p;
    if (sel < 2) {
        short* outg = (sel == 0) ? out0 : out1;
        #pragma unroll
        for (int rt = 0; rt < RT; ++rt)
            #pragma unroll
            for (int ct = 0; ct < CT; ++ct) {
                const int d = nb + wc + ct*16 + l;
                const float bsv = bias[d];
                const int h = d >> 6, hd = d & 63;
                #pragma unroll
                for (int r = 0; r < 4; ++r) {
                    const int m = m0 + wr + rt*16 + qd*4 + r;
                    const int bb = m >> 11, s = m & 2047;
                    float val = acc[rt][ct][r] + bsv;
                    float pv = __shfl_xor(val, 1);
                    const float* f = freqs + (size_t)s*128 + (size_t)(hd >> 1)*4;
                    float o = (d & 1) ? (f[2]*pv + f[3]*val) : (f[0]*val + f[1]*pv);
                    outg[((size_t)(bb*16 + h)*2048 + s)*64 + hd] = f2bf(o);
                }
            }
    } else {
        #pragma unroll
        for (int rt = 0; rt < RT; ++rt)
            #pragma unroll
            for (int ct = 0; ct < CT; ++ct) {
                const int d = nb + wc + ct*16 + l;
                const float bsv = bias[d];
                const int h = d >> 6, hd = d & 63;
                const int m0r = m0 + wr + rt*16 + qd*4;
                const int bb = m0r >> 11, s0 = m0r & 2047;
                short4v pk;
                #pragma unroll
                for (int r = 0; r < 4; ++r) pk[r] = f2bf(acc[rt][ct][r] + bsv);
                *(short4v*)&out2[((size_t)(bb*16 + h)*64 + hd)*2048 + s0] = pk;  // v^T
            }
    }
}

// ---------------------------------------------------------------------------
// proj GEMM — BK=64, 64x64 tile, sa2 counted stage-ahead-2 (R12's proj,
// now deconfounded from the attn change). 16 periods instead of 32 — proj
// is period-bound (~130 TF at 32 periods) and pays the same sync cost as
// QKV for 1/3 the FLOPs. 3 static buffers, 48 KB LDS -> 3 blocks/CU,
// grid (16,64)=1024. LDS rows 64 shorts (128B); data slot s of row r at
// LDS slot s^(r&7). Per chunk: 4 gloads, 8 MFMA/wave;
// vwait<4> -> bar -> STAGE(c+2) -> COMP(c).
__global__ __launch_bounds__(256) void gemm_proj64(
    const short* __restrict__ A, const short* __restrict__ Bw,
    const float* __restrict__ b0p, float* __restrict__ out)
{
    __shared__ __align__(16) short A0[64*64];
    __shared__ __align__(16) short A1[64*64];
    __shared__ __align__(16) short A2[64*64];
    __shared__ __align__(16) short B0[64*64];
    __shared__ __align__(16) short B1[64*64];
    __shared__ __align__(16) short B2[64*64];
    const int t = threadIdx.x;
    const int w = t >> 6;
    const int lane = t & 63;
    const int qd = lane >> 4, l = lane & 15;
    const int l7 = lane & 7;
    const int n0 = blockIdx.x * 64, m0 = blockIdx.y * 64;
    const int wr = (w >> 1) * 32, wc = (w & 1) * 32;
    const int rl  = lane >> 3;
    const int ss8 = ((lane & 7) ^ rl) << 3;    // pre-swizzled source slot

    f32x4 acc[2][2] = {};

    auto STAGE = [&](int c, short* As, short* Bss) {
        const int k0 = c * 64;
        #pragma unroll
        for (int j = 0; j < 2; ++j) {
            const int r0 = (j*4 + w) * 8;
            gload_lds16(A  + (size_t)(m0 + r0 + rl)*1024 + k0 + ss8, &As[r0*64]);
            gload_lds16(Bw + (size_t)(n0 + r0 + rl)*1024 + k0 + ss8, &Bss[r0*64]);
        }
    };

    auto COMP = [&](const short* As, const short* Bss) {
        #pragma unroll
        for (int kk = 0; kk < 2; ++kk) {
            short8 af[2], bfr[2];
            #pragma unroll
            for (int rt = 0; rt < 2; ++rt)
                af[rt] = *(const short8*)&As[(wr + rt*16 + l)*64 + (((kk*4 + qd) ^ l7) << 3)];
            #pragma unroll
            for (int ct = 0; ct < 2; ++ct)
                bfr[ct] = *(const short8*)&Bss[(wc + ct*16 + l)*64 + (((kk*4 + qd) ^ l7) << 3)];
            #pragma unroll
            for (int rt = 0; rt < 2; ++rt)
                #pragma unroll
                for (int ct = 0; ct < 2; ++ct)
                    acc[rt][ct] = __builtin_amdgcn_mfma_f32_16x16x32_bf16(af[rt], bfr[ct], acc[rt][ct], 0, 0, 0);
        }
    };

    // 16 chunks of K=64; chunk c -> buffer c%3; stage-ahead-2, 1 barrier/chunk.
    STAGE(0, A0, B0);
    STAGE(1, A1, B1);
    for (int p = 0; p <= 9; p += 3) {       // computes 0..11, stages 2..13
        vwait<4>(); bar();
        STAGE(p + 2, A2, B2);
        COMP(A0, B0);
        vwait<4>(); bar();
        STAGE(p + 3, A0, B0);
        COMP(A1, B1);
        vwait<4>(); bar();
        STAGE(p + 4, A1, B1);
        COMP(A2, B2);
    }
    vwait<4>(); bar();
    STAGE(14, A2, B2);
    COMP(A0, B0);                           // chunk 12
    vwait<4>(); bar();
    STAGE(15, A0, B0);
    COMP(A1, B1);                           // chunk 13
    vwait<4>(); bar();
    COMP(A2, B2);                           // chunk 14
    vwait<0>(); bar();
    COMP(A0, B0);                           // chunk 15

    #pragma unroll
    for (int rt = 0; rt < 2; ++rt)
        #pragma unroll
        for (int ct = 0; ct < 2; ++ct) {
            const int n = n0 + wc + ct*16 + l;
            const float bias = b0p[n];
            #pragma unroll
            for (int r = 0; r < 4; ++r) {
                const int m = m0 + wr + rt*16 + qd*4 + r;
                out[(size_t)m*1024 + n] = acc[rt][ct][r] + bias;
            }
        }
}

// ---------------------------------------------------------------------------
// MFMA flash attention — R9/sa2 version verbatim (best measured): 8 waves x
// 16 queries, 3 static K/V buffers, one s_barrier + counted vwait<2> per
// K-tile, stage-ahead-2. K/V^T staged via global_load_lds with PRE-SWIZZLED
// global source (16B slot s of row r holds slot s^(r&7), 128B rows); all
// b128 reads apply the same XOR -> conflict-free. P in a separate buffer.
__global__ __launch_bounds__(512) void attn_mfma(
    const short* __restrict__ qg, const short* __restrict__ kg,
    const short* __restrict__ vtg, short* __restrict__ og)
{
    __shared__ __align__(16) short K0[64*64];
    __shared__ __align__(16) short K1[64*64];
    __shared__ __align__(16) short K2[64*64];
    __shared__ __align__(16) short V0[64*64];
    __shared__ __align__(16) short V1[64*64];
    __shared__ __align__(16) short V2[64*64];
    __shared__ __align__(16) short Pb[128*64];

    const int t = threadIdx.x;
    const int w = t >> 6;                  // 0..7
    const int lane = t & 63;
    const int qd = lane >> 4, l = lane & 15;
    const int l7 = lane & 7;
    const int q0 = blockIdx.x * 128;
    const int bh = blockIdx.y;

    const int rl  = lane >> 3;
    const int ss8 = ((lane & 7) ^ rl) << 3;

    short8 qf[2];
    const short* qb = qg + ((size_t)bh*2048 + q0 + w*16)*64;
    #pragma unroll
    for (int kf = 0; kf < 2; ++kf)
        qf[kf] = *(const short8*)&qb[l*64 + kf*32 + qd*8];

    f32x4 oacc[4] = {};
    float lsum = 0.f;

    const short* kbase = kg  + (size_t)bh*2048*64;
    const short* vbase = vtg + (size_t)bh*64*2048;
    const float SC = 0.125f * 1.44269504088896340736f;

    auto PREF = [&](int c, short* Kd, short* Vd) {
        gload_lds16(kbase + (size_t)(c*64 + w*8 + rl)*64 + ss8,   &Kd[(w*8)*64]);
        gload_lds16(vbase + (size_t)(w*8 + rl)*2048 + c*64 + ss8, &Vd[(w*8)*64]);
    };

    auto TILE = [&](const short* Kc, const short* Vc) {
        f32x4 sacc[4] = {};
        #pragma unroll
        for (int ct = 0; ct < 4; ++ct) {
            short8 k0f = *(const short8*)&Kc[(ct*16 + l)*64 + (((0 + qd) ^ l7) << 3)];
            short8 k1f = *(const short8*)&Kc[(ct*16 + l)*64 + (((4 + qd) ^ l7) << 3)];
            sacc[ct] = __builtin_amdgcn_mfma_f32_16x16x32_bf16(k0f, qf[0], sacc[ct], 0, 0, 0);
            sacc[ct] = __builtin_amdgcn_mfma_f32_16x16x32_bf16(k1f, qf[1], sacc[ct], 0, 0, 0);
        }
        #pragma unroll
        for (int ct = 0; ct < 4; ++ct) {
            float p0 = exp2f(sacc[ct][0] * SC);
            float p1 = exp2f(sacc[ct][1] * SC);
            float p2 = exp2f(sacc[ct][2] * SC);
            float p3 = exp2f(sacc[ct][3] * SC);
            lsum += (p0 + p1) + (p2 + p3);
            union { unsigned u[2]; short4v s; } cv;
            asm("v_cvt_pk_bf16_f32 %0, %1, %2" : "=v"(cv.u[0]) : "v"(p0), "v"(p1));
            asm("v_cvt_pk_bf16_f32 %0, %1, %2" : "=v"(cv.u[1]) : "v"(p2), "v"(p3));
            *(short4v*)&Pb[(w*16 + l)*64 + (((ct*32 + qd*8) ^ (l7 << 4)) >> 1)] = cv.s;
        }
        #pragma unroll
        for (int kf = 0; kf < 2; ++kf) {
            const int so = ((kf*4 + qd) ^ l7) << 3;
            short8 pa = *(const short8*)&Pb[(w*16 + l)*64 + so];
            #pragma unroll
            for (int ht = 0; ht < 4; ++ht) {
                short8 vb = *(const short8*)&Vc[(ht*16 + l)*64 + so];
                oacc[ht] = __builtin_amdgcn_mfma_f32_16x16x32_bf16(pa, vb, oacc[ht], 0, 0, 0);
            }
        }
    };

    PREF(0, K0, V0);
    PREF(1, K1, V1);
    for (int p = 0; p <= 27; p += 3) {
        vwait<2>(); bar();
        PREF(p + 2, K2, V2);
        TILE(K0, V0);
        vwait<2>(); bar();
        PREF(p + 3, K0, V0);
        TILE(K1, V1);
        vwait<2>(); bar();
        PREF(p + 4, K1, V1);
        TILE(K2, V2);
    }
    vwait<2>(); bar();
    TILE(K0, V0);
    vwait<0>(); bar();
    TILE(K1, V1);

    lsum += __shfl_xor(lsum, 16);
    lsum += __shfl_xor(lsum, 32);
    float inv[4];
    #pragma unroll
    for (int r = 0; r < 4; ++r)
        inv[r] = 1.0f / __shfl(lsum, qd*4 + r);

    const int bb = bh >> 4, h = bh & 15;
    #pragma unroll
    for (int ht = 0; ht < 4; ++ht)
        #pragma unroll
        for (int r = 0; r < 4; ++r) {
            const int s = q0 + w*16 + qd*4 + r;
            og[((size_t)bb*2048 + s)*1024 + h*64 + ht*16 + l] =
                f2bf(oacc[ht][r] * inv[r]);
        }
}

// ---------------------------------------------------------------------------
extern "C" void kernel_launch(void* const* d_in, const int* in_sizes, int n_in,
                              void* d_out, int out_size, void* d_ws, size_t ws_size,
                              hipStream_t stream)
{
    const float* x  = (const float*)d_in[0];
    const float* fr = (const float*)d_in[1];
    const float* Wq = (const float*)d_in[2];
    const float* bq = (const float*)d_in[3];
    const float* Wk = (const float*)d_in[4];
    const float* bk = (const float*)d_in[5];
    const float* Wv = (const float*)d_in[6];
    const float* bv = (const float*)d_in[7];
    const float* Wo = (const float*)d_in[8];
    const float* bo = (const float*)d_in[9];
    float* out = (float*)d_out;

    short* ws    = (short*)d_ws;
    short* xb    = ws;                  // 4,194,304
    short* Wqkvb = xb    + 4194304;     // 3,145,728
    short* Wob   = Wqkvb + 3145728;     // 1,048,576
    short* qg    = Wob   + 1048576;     // [BH,S,HD]
    short* kg    = qg    + 4194304;     // [BH,S,HD]
    short* vtg   = kg    + 4194304;     // [BH,HD,S]
    short* og    = vtg   + 4194304;     // [B,S,H*HD]

    cast_all_kernel<<<8192, 256, 0, stream>>>(x, Wq, Wk, Wv, Wo, xb, Wqkvb, Wob);
    gemm_qkv<<<dim3(24, 32), 256, 0, stream>>>(xb, Wqkvb, bq, bk, bv, fr, qg, kg, vtg);
    attn_mfma<<<dim3(16, 32), 512, 0, stream>>>(qg, kg, vtg, og);
    gemm_proj64<<<dim3(16, 64), 256, 0, stream>>>(og, Wob, bo, out);
}

// Round 14
// 239.425 us; speedup vs baseline: 1.0627x; 1.0046x over previous
//
#include <hip/hip_runtime.h>
#include <cmath>

#define B_ 2
#define S_ 2048
#define D_ 1024
#define H_ 16
#define HD_ 64
#define M_ 4096   // B*S

typedef __attribute__((ext_vector_type(8))) short short8;
typedef __attribute__((ext_vector_type(4))) short short4v;
typedef __attribute__((ext_vector_type(4))) float f32x4;

// round-to-nearest-even f32 -> bf16 (values finite here)
__device__ __forceinline__ short f2bf(float x) {
    unsigned u = __builtin_bit_cast(unsigned, x);
    u += 0x7fffu + ((u >> 16) & 1u);
    return (short)(u >> 16);
}

__device__ __forceinline__ void gload_lds16(const short* g, short* l) {
    __builtin_amdgcn_global_load_lds(
        (const __attribute__((address_space(1))) unsigned int*)g,
        (__attribute__((address_space(3))) unsigned int*)l, 16, 0, 0);
}

// counted vmcnt wait — prefetches stay in flight across barriers
template<int N> __device__ __forceinline__ void vwait() {
    if constexpr (N == 0) asm volatile("s_waitcnt vmcnt(0)" ::: "memory");
    else if constexpr (N == 2) asm volatile("s_waitcnt vmcnt(2)" ::: "memory");
    else if constexpr (N == 3) asm volatile("s_waitcnt vmcnt(3)" ::: "memory");
    else if constexpr (N == 4) asm volatile("s_waitcnt vmcnt(4)" ::: "memory");
}
__device__ __forceinline__ void bar() { __builtin_amdgcn_s_barrier(); }

// ---------------------------------------------------------------------------
// cast fp32 inputs to bf16
__global__ __launch_bounds__(256) void cast_all_kernel(
    const float* __restrict__ x,  const float* __restrict__ Wq,
    const float* __restrict__ Wk, const float* __restrict__ Wv,
    const float* __restrict__ Wo,
    short* __restrict__ xb, short* __restrict__ Wqkvb, short* __restrict__ Wob)
{
    const size_t i = (size_t)blockIdx.x * 256 + threadIdx.x;  // float4 index
    const float* src; short* dst; size_t off;
    if (i < 1048576)      { src = x;  dst = xb;              off = i; }
    else if (i < 1310720) { src = Wq; dst = Wqkvb;           off = i - 1048576; }
    else if (i < 1572864) { src = Wk; dst = Wqkvb + 1048576; off = i - 1310720; }
    else if (i < 1835008) { src = Wv; dst = Wqkvb + 2097152; off = i - 1572864; }
    else                  { src = Wo; dst = Wob;             off = i - 1835008; }
    float4 v = ((const float4*)src)[off];
    short4v o = { f2bf(v.x), f2bf(v.y), f2bf(v.z), f2bf(v.w) };
    ((short4v*)dst)[off] = o;
}

// ---------------------------------------------------------------------------
// QKV GEMM — sa2 stage-ahead-2, BK=32, 128x128 (R9 schedule verbatim) +
// XCD-contiguous block remap (T1). Default dispatch round-robins blocks
// across the 8 XCDs, so blocks sharing A/B panels populate 8 separate L2s
// -> staged loads are L3-latency (~500-700cy); with T = L/2 equilibrium
// that IS the period. Remap: xcd = bid&7 gets a contiguous 8 m-rows x 12
// n-cols chunk -> per-XCD working set 2 MB A-panel + 3 MB B-half = 5 MB
// (vs 14 MB), pushing staged loads toward L2 hits (~200cy).
// Bijective: (mr,nc) = ((xcd&3)*8 + idx/12, (xcd>>2)*12 + idx%12).
// 3 static buffers; per chunk: vwait<4> -> s_barrier -> STAGE(c+2) -> COMP(c).
// LDS rows 32 shorts (64B); data slot s of row r at LDS slot s^((r>>1)&3).
// 48 KB LDS -> 3 blocks/CU, grid 768 all-resident.
// Fused epilogue: q,k bias+RoPE -> [BH,S,HD]; v bias -> [BH,HD,S].
__global__ __launch_bounds__(256) void gemm_qkv(
    const short* __restrict__ A, const short* __restrict__ Bw,
    const float* __restrict__ b0p, const float* __restrict__ b1p, const float* __restrict__ b2p,
    const float* __restrict__ freqs,
    short* __restrict__ out0, short* __restrict__ out1, short* __restrict__ out2)
{
    constexpr int TM = 128, TN = 128, RT = 4, CT = 4, LPC = 4;
    __shared__ __align__(16) short A0[TM*32];
    __shared__ __align__(16) short A1[TM*32];
    __shared__ __align__(16) short A2[TM*32];
    __shared__ __align__(16) short B0[TN*32];
    __shared__ __align__(16) short B1[TN*32];
    __shared__ __align__(16) short B2[TN*32];
    const int t = threadIdx.x;
    const int w = t >> 6;
    const int lane = t & 63;
    const int qd = lane >> 4, l = lane & 15;
    // XCD-contiguous remap (bijective on 768 = 8 x (8x12))
    const int bid = blockIdx.x;
    const int xcd = bid & 7, idx = bid >> 3;       // idx 0..95
    const int mr = (xcd & 3) * 8 + idx / 12;       // 0..31
    const int nc = (xcd >> 2) * 12 + idx % 12;     // 0..23
    const int n0 = nc * TN, m0 = mr * TM;
    const int wr = (w >> 1) * (TM/2), wc = (w & 1) * (TN/2);
    const int srow  = lane >> 2;
    const int sslot = ((lane & 3) ^ ((lane >> 3) & 3)) * 8;
    const int rsw = (l >> 1) & 3;

    f32x4 acc[RT][CT] = {};

    auto STAGE = [&](int c, short* As, short* Bss) {
        const int k0 = c * 32;
        #pragma unroll
        for (int j = 0; j < TM/64; ++j) {
            const int r0 = (j*4 + w) * 16;
            gload_lds16(A + (size_t)(m0 + r0 + srow)*1024 + k0 + sslot, &As[r0*32]);
        }
        #pragma unroll
        for (int j = 0; j < TN/64; ++j) {
            const int r0 = (j*4 + w) * 16;
            gload_lds16(Bw + (size_t)(n0 + r0 + srow)*1024 + k0 + sslot, &Bss[r0*32]);
        }
    };

    auto COMP = [&](const short* As, const short* Bss) {
        short8 af[RT], bfr[CT];
        #pragma unroll
        for (int rt = 0; rt < RT; ++rt)
            af[rt] = *(const short8*)&As[(wr + rt*16 + l)*32 + ((qd ^ rsw) << 3)];
        #pragma unroll
        for (int ct = 0; ct < CT; ++ct)
            bfr[ct] = *(const short8*)&Bss[(wc + ct*16 + l)*32 + ((qd ^ rsw) << 3)];
        #pragma unroll
        for (int rt = 0; rt < RT; ++rt)
            #pragma unroll
            for (int ct = 0; ct < CT; ++ct)
                acc[rt][ct] = __builtin_amdgcn_mfma_f32_16x16x32_bf16(af[rt], bfr[ct], acc[rt][ct], 0, 0, 0);
    };

    STAGE(0, A0, B0);
    STAGE(1, A1, B1);
    for (int p = 0; p <= 27; p += 3) {
        vwait<LPC>(); bar();
        STAGE(p + 2, A2, B2);
        COMP(A0, B0);
        vwait<LPC>(); bar();
        STAGE(p + 3, A0, B0);
        COMP(A1, B1);
        vwait<LPC>(); bar();
        STAGE(p + 4, A1, B1);
        COMP(A2, B2);
    }
    vwait<LPC>(); bar();
    COMP(A0, B0);
    vwait<0>(); bar();
    COMP(A1, B1);

    const int sel = n0 >> 10;          // 0=q 1=k 2=v (uniform per block)
    const int nb = n0 & 1023;
    const float* bias = (sel == 0) ? b0p : (sel == 1) ? b1p : b2p;
    if (sel < 2) {
        short* outg = (sel == 0) ? out0 : out1;
        #pragma unroll
        for (int rt = 0; rt < RT; ++rt)
            #pragma unroll
            for (int ct = 0; ct < CT; ++ct) {
                const int d = nb + wc + ct*16 + l;
                const float bsv = bias[d];
                const int h = d >> 6, hd = d & 63;
                #pragma unroll
                for (int r = 0; r < 4; ++r) {
                    const int m = m0 + wr + rt*16 + qd*4 + r;
                    const int bb = m >> 11, s = m & 2047;
                    float val = acc[rt][ct][r] + bsv;
                    float pv = __shfl_xor(val, 1);
                    const float* f = freqs + (size_t)s*128 + (size_t)(hd >> 1)*4;
                    float o = (d & 1) ? (f[2]*pv + f[3]*val) : (f[0]*val + f[1]*pv);
                    outg[((size_t)(bb*16 + h)*2048 + s)*64 + hd] = f2bf(o);
                }
            }
    } else {
        #pragma unroll
        for (int rt = 0; rt < RT; ++rt)
            #pragma unroll
            for (int ct = 0; ct < CT; ++ct) {
                const int d = nb + wc + ct*16 + l;
                const float bsv = bias[d];
                const int h = d >> 6, hd = d & 63;
                const int m0r = m0 + wr + rt*16 + qd*4;
                const int bb = m0r >> 11, s0 = m0r & 2047;
                short4v pk;
                #pragma unroll
                for (int r = 0; r < 4; ++r) pk[r] = f2bf(acc[rt][ct][r] + bsv);
                *(short4v*)&out2[((size_t)(bb*16 + h)*64 + hd)*2048 + s0] = pk;  // v^T
            }
    }
}

// ---------------------------------------------------------------------------
// proj GEMM — BK=64, 64x64 tile, sa2 counted stage-ahead-2 (R13 schedule)
// + XCD-contiguous remap: per-XCD chunk = 8 m-rows x all 16 n-cols ->
// working set 1 MB og-panel + 2 MB Wo = 3 MB, fully L2-resident.
// Bijective on 1024 = 8 x (8x16): mr = xcd*8 + idx/16, nc = idx%16.
// 3 static buffers, 48 KB LDS -> 3 blocks/CU, grid 1024.
// LDS rows 64 shorts (128B); data slot s of row r at LDS slot s^(r&7).
__global__ __launch_bounds__(256) void gemm_proj64(
    const short* __restrict__ A, const short* __restrict__ Bw,
    const float* __restrict__ b0p, float* __restrict__ out)
{
    __shared__ __align__(16) short A0[64*64];
    __shared__ __align__(16) short A1[64*64];
    __shared__ __align__(16) short A2[64*64];
    __shared__ __align__(16) short B0[64*64];
    __shared__ __align__(16) short B1[64*64];
    __shared__ __align__(16) short B2[64*64];
    const int t = threadIdx.x;
    const int w = t >> 6;
    const int lane = t & 63;
    const int qd = lane >> 4, l = lane & 15;
    const int l7 = lane & 7;
    // XCD-contiguous remap (bijective on 1024 = 8 x (8x16))
    const int bid = blockIdx.x;
    const int xcd = bid & 7, idx = bid >> 3;   // idx 0..127
    const int mr = xcd * 8 + (idx >> 4);       // 0..63
    const int nc = idx & 15;                   // 0..15
    const int n0 = nc * 64, m0 = mr * 64;
    const int wr = (w >> 1) * 32, wc = (w & 1) * 32;
    const int rl  = lane >> 3;
    const int ss8 = ((lane & 7) ^ rl) << 3;    // pre-swizzled source slot

    f32x4 acc[2][2] = {};

    auto STAGE = [&](int c, short* As, short* Bss) {
        const int k0 = c * 64;
        #pragma unroll
        for (int j = 0; j < 2; ++j) {
            const int r0 = (j*4 + w) * 8;
            gload_lds16(A  + (size_t)(m0 + r0 + rl)*1024 + k0 + ss8, &As[r0*64]);
            gload_lds16(Bw + (size_t)(n0 + r0 + rl)*1024 + k0 + ss8, &Bss[r0*64]);
        }
    };

    auto COMP = [&](const short* As, const short* Bss) {
        #pragma unroll
        for (int kk = 0; kk < 2; ++kk) {
            short8 af[2], bfr[2];
            #pragma unroll
            for (int rt = 0; rt < 2; ++rt)
                af[rt] = *(const short8*)&As[(wr + rt*16 + l)*64 + (((kk*4 + qd) ^ l7) << 3)];
            #pragma unroll
            for (int ct = 0; ct < 2; ++ct)
                bfr[ct] = *(const short8*)&Bss[(wc + ct*16 + l)*64 + (((kk*4 + qd) ^ l7) << 3)];
            #pragma unroll
            for (int rt = 0; rt < 2; ++rt)
                #pragma unroll
                for (int ct = 0; ct < 2; ++ct)
                    acc[rt][ct] = __builtin_amdgcn_mfma_f32_16x16x32_bf16(af[rt], bfr[ct], acc[rt][ct], 0, 0, 0);
        }
    };

    // 16 chunks of K=64; chunk c -> buffer c%3; stage-ahead-2, 1 barrier/chunk.
    STAGE(0, A0, B0);
    STAGE(1, A1, B1);
    for (int p = 0; p <= 9; p += 3) {       // computes 0..11, stages 2..13
        vwait<4>(); bar();
        STAGE(p + 2, A2, B2);
        COMP(A0, B0);
        vwait<4>(); bar();
        STAGE(p + 3, A0, B0);
        COMP(A1, B1);
        vwait<4>(); bar();
        STAGE(p + 4, A1, B1);
        COMP(A2, B2);
    }
    vwait<4>(); bar();
    STAGE(14, A2, B2);
    COMP(A0, B0);                           // chunk 12
    vwait<4>(); bar();
    STAGE(15, A0, B0);
    COMP(A1, B1);                           // chunk 13
    vwait<4>(); bar();
    COMP(A2, B2);                           // chunk 14
    vwait<0>(); bar();
    COMP(A0, B0);                           // chunk 15

    #pragma unroll
    for (int rt = 0; rt < 2; ++rt)
        #pragma unroll
        for (int ct = 0; ct < 2; ++ct) {
            const int n = n0 + wc + ct*16 + l;
            const float bias = b0p[n];
            #pragma unroll
            for (int r = 0; r < 4; ++r) {
                const int m = m0 + wr + rt*16 + qd*4 + r;
                out[(size_t)m*1024 + n] = acc[rt][ct][r] + bias;
            }
        }
}

// ---------------------------------------------------------------------------
// MFMA flash attention — R9/sa2 schedule verbatim + XCD-contiguous remap:
// per-XCD chunk = 4 bh x 16 q-blocks -> K/V working set 4 x 512 KB = 2 MB,
// fully L2-resident (default dispatch re-fetches each bh's K/V on all 8
// XCDs). Bijective on 512 = 8 x (4x16): bh = xcd*4 + idx/16, q0 = (idx%16)*128.
// 8 waves x 16 queries, 3 static K/V buffers, one s_barrier + counted
// vwait<2> per K-tile, stage-ahead-2. K/V^T staged via global_load_lds with
// PRE-SWIZZLED global source (16B slot s of row r holds slot s^(r&7), 128B
// rows); all b128 reads apply the same XOR -> conflict-free. P separate.
__global__ __launch_bounds__(512) void attn_mfma(
    const short* __restrict__ qg, const short* __restrict__ kg,
    const short* __restrict__ vtg, short* __restrict__ og)
{
    __shared__ __align__(16) short K0[64*64];
    __shared__ __align__(16) short K1[64*64];
    __shared__ __align__(16) short K2[64*64];
    __shared__ __align__(16) short V0[64*64];
    __shared__ __align__(16) short V1[64*64];
    __shared__ __align__(16) short V2[64*64];
    __shared__ __align__(16) short Pb[128*64];

    const int t = threadIdx.x;
    const int w = t >> 6;                  // 0..7
    const int lane = t & 63;
    const int qd = lane >> 4, l = lane & 15;
    const int l7 = lane & 7;
    // XCD-contiguous remap (bijective on 512 = 8 x (4x16))
    const int bid = blockIdx.x;
    const int xcd = bid & 7, idx = bid >> 3;   // idx 0..63
    const int bh = xcd * 4 + (idx >> 4);       // 0..31
    const int q0 = (idx & 15) * 128;

    const int rl  = lane >> 3;
    const int ss8 = ((lane & 7) ^ rl) << 3;

    short8 qf[2];
    const short* qb = qg + ((size_t)bh*2048 + q0 + w*16)*64;
    #pragma unroll
    for (int kf = 0; kf < 2; ++kf)
        qf[kf] = *(const short8*)&qb[l*64 + kf*32 + qd*8];

    f32x4 oacc[4] = {};
    float lsum = 0.f;

    const short* kbase = kg  + (size_t)bh*2048*64;
    const short* vbase = vtg + (size_t)bh*64*2048;
    const float SC = 0.125f * 1.44269504088896340736f;

    auto PREF = [&](int c, short* Kd, short* Vd) {
        gload_lds16(kbase + (size_t)(c*64 + w*8 + rl)*64 + ss8,   &Kd[(w*8)*64]);
        gload_lds16(vbase + (size_t)(w*8 + rl)*2048 + c*64 + ss8, &Vd[(w*8)*64]);
    };

    auto TILE = [&](const short* Kc, const short* Vc) {
        f32x4 sacc[4] = {};
        #pragma unroll
        for (int ct = 0; ct < 4; ++ct) {
            short8 k0f = *(const short8*)&Kc[(ct*16 + l)*64 + (((0 + qd) ^ l7) << 3)];
            short8 k1f = *(const short8*)&Kc[(ct*16 + l)*64 + (((4 + qd) ^ l7) << 3)];
            sacc[ct] = __builtin_amdgcn_mfma_f32_16x16x32_bf16(k0f, qf[0], sacc[ct], 0, 0, 0);
            sacc[ct] = __builtin_amdgcn_mfma_f32_16x16x32_bf16(k1f, qf[1], sacc[ct], 0, 0, 0);
        }
        #pragma unroll
        for (int ct = 0; ct < 4; ++ct) {
            float p0 = exp2f(sacc[ct][0] * SC);
            float p1 = exp2f(sacc[ct][1] * SC);
            float p2 = exp2f(sacc[ct][2] * SC);
            float p3 = exp2f(sacc[ct][3] * SC);
            lsum += (p0 + p1) + (p2 + p3);
            union { unsigned u[2]; short4v s; } cv;
            asm("v_cvt_pk_bf16_f32 %0, %1, %2" : "=v"(cv.u[0]) : "v"(p0), "v"(p1));
            asm("v_cvt_pk_bf16_f32 %0, %1, %2" : "=v"(cv.u[1]) : "v"(p2), "v"(p3));
            *(short4v*)&Pb[(w*16 + l)*64 + (((ct*32 + qd*8) ^ (l7 << 4)) >> 1)] = cv.s;
        }
        #pragma unroll
        for (int kf = 0; kf < 2; ++kf) {
            const int so = ((kf*4 + qd) ^ l7) << 3;
            short8 pa = *(const short8*)&Pb[(w*16 + l)*64 + so];
            #pragma unroll
            for (int ht = 0; ht < 4; ++ht) {
                short8 vb = *(const short8*)&Vc[(ht*16 + l)*64 + so];
                oacc[ht] = __builtin_amdgcn_mfma_f32_16x16x32_bf16(pa, vb, oacc[ht], 0, 0, 0);
            }
        }
    };

    PREF(0, K0, V0);
    PREF(1, K1, V1);
    for (int p = 0; p <= 27; p += 3) {
        vwait<2>(); bar();
        PREF(p + 2, K2, V2);
        TILE(K0, V0);
        vwait<2>(); bar();
        PREF(p + 3, K0, V0);
        TILE(K1, V1);
        vwait<2>(); bar();
        PREF(p + 4, K1, V1);
        TILE(K2, V2);
    }
    vwait<2>(); bar();
    TILE(K0, V0);
    vwait<0>(); bar();
    TILE(K1, V1);

    lsum += __shfl_xor(lsum, 16);
    lsum += __shfl_xor(lsum, 32);
    float inv[4];
    #pragma unroll
    for (int r = 0; r < 4; ++r)
        inv[r] = 1.0f / __shfl(lsum, qd*4 + r);

    const int bb = bh >> 4, h = bh & 15;
    #pragma unroll
    for (int ht = 0; ht < 4; ++ht)
        #pragma unroll
        for (int r = 0; r < 4; ++r) {
            const int s = q0 + w*16 + qd*4 + r;
            og[((size_t)bb*2048 + s)*1024 + h*64 + ht*16 + l] =
                f2bf(oacc[ht][r] * inv[r]);
        }
}

// ---------------------------------------------------------------------------
extern "C" void kernel_launch(void* const* d_in, const int* in_sizes, int n_in,
                              void* d_out, int out_size, void* d_ws, size_t ws_size,
                              hipStream_t stream)
{
    const float* x  = (const float*)d_in[0];
    const float* fr = (const float*)d_in[1];
    const float* Wq = (const float*)d_in[2];
    const float* bq = (const float*)d_in[3];
    const float* Wk = (const float*)d_in[4];
    const float* bk = (const float*)d_in[5];
    const float* Wv = (const float*)d_in[6];
    const float* bv = (const float*)d_in[7];
    const float* Wo = (const float*)d_in[8];
    const float* bo = (const float*)d_in[9];
    float* out = (float*)d_out;

    short* ws    = (short*)d_ws;
    short* xb    = ws;                  // 4,194,304
    short* Wqkvb = xb    + 4194304;     // 3,145,728
    short* Wob   = Wqkvb + 3145728;     // 1,048,576
    short* qg    = Wob   + 1048576;     // [BH,S,HD]
    short* kg    = qg    + 4194304;     // [BH,S,HD]
    short* vtg   = kg    + 4194304;     // [BH,HD,S]
    short* og    = vtg   + 4194304;     // [B,S,H*HD]

    cast_all_kernel<<<8192, 256, 0, stream>>>(x, Wq, Wk, Wv, Wo, xb, Wqkvb, Wob);
    gemm_qkv<<<768, 256, 0, stream>>>(xb, Wqkvb, bq, bk, bv, fr, qg, kg, vtg);
    attn_mfma<<<512, 512, 0, stream>>>(qg, kg, vtg, og);
    gemm_proj64<<<1024, 256, 0, stream>>>(og, Wob, bo, out);
}